// Round 1
// baseline (4459.602 us; speedup 1.0000x reference)
//
#include <hip/hip_runtime.h>
#include <math.h>

#define NN 2500
#define EE 50000
#define CC 128
#define LL 25
#define LP 32          // padded row length for transposed LDS tiles
#define HH 8
#define AA 64
#define VV 16
#define FF 128
#define NBASIS 600
#define EFD (NBASIS + 2*CC)   // 856

__device__ __forceinline__ float silu_f(float x){ return x / (1.0f + expf(-x)); }

__device__ __forceinline__ void fma16(float (&cm)[4][4], const float4& av, const float4& bv){
  cm[0][0]+=av.x*bv.x; cm[0][1]+=av.x*bv.y; cm[0][2]+=av.x*bv.z; cm[0][3]+=av.x*bv.w;
  cm[1][0]+=av.y*bv.x; cm[1][1]+=av.y*bv.y; cm[1][2]+=av.y*bv.z; cm[1][3]+=av.y*bv.w;
  cm[2][0]+=av.z*bv.x; cm[2][1]+=av.z*bv.y; cm[2][2]+=av.z*bv.z; cm[2][3]+=av.z*bv.w;
  cm[3][0]+=av.w*bv.x; cm[3][1]+=av.w*bv.y; cm[3][2]+=av.w*bv.z; cm[3][3]+=av.w*bv.w;
}

// ---------------- edge sort by dst (counting sort) ----------------
__global__ void k_hist(const int* __restrict__ ei, int* __restrict__ counts){
  int e = blockIdx.x*256 + threadIdx.x;
  if (e < EE) atomicAdd(&counts[ei[EE+e]], 1);
}

__global__ void k_scan(const int* __restrict__ counts, int* __restrict__ offsets){
  __shared__ int part[256];
  __shared__ int partx[257];
  int t = threadIdx.x;
  const int chunk = (NN + 255)/256;   // 10
  int base = t*chunk;
  int s = 0;
  for (int i=0;i<chunk;i++){ int idx=base+i; if (idx<NN) s += counts[idx]; }
  part[t] = s;
  __syncthreads();
  if (t==0){ int acc=0; for (int i=0;i<256;i++){ partx[i]=acc; acc+=part[i]; } partx[256]=acc; }
  __syncthreads();
  int acc = partx[t];
  for (int i=0;i<chunk;i++){ int idx=base+i; if (idx<NN){ offsets[idx]=acc; acc+=counts[idx]; } }
  if (t==0) offsets[NN] = partx[256];
}

__global__ void k_scatter(const int* __restrict__ ei, const int* __restrict__ offsets,
                          int* __restrict__ cursor, int* __restrict__ order){
  int e = blockIdx.x*256 + threadIdx.x;
  if (e < EE){
    int d = ei[EE+e];
    int p = atomicAdd(&cursor[d], 1);
    order[offsets[d]+p] = e;
  }
}

// ---------------- init x: only l=0 row populated ----------------
__global__ void k_init_x(const int* __restrict__ zn, const float* __restrict__ atom_emb,
                         float* __restrict__ x){
  int idx = blockIdx.x*256 + threadIdx.x;   // N*LL*CC = 8,000,000 (exact multiple of 256)
  int n = idx / (LL*CC);
  int r = idx - n*(LL*CC);
  float v = 0.0f;
  if (r < CC) v = atom_emb[zn[n]*CC + r];
  x[idx] = v;
}

// ---------------- edge scalar features -> rad0, rad1 ----------------
// 8 edges per block; ef never hits HBM (only rad = ef @ W_rad[l] is stored)
__global__ __launch_bounds__(256)
void k_edge(const int* __restrict__ ei, const int* __restrict__ zn,
            const float* __restrict__ pos,
            const float* __restrict__ src_emb, const float* __restrict__ dst_emb,
            const float* __restrict__ W_e1, const float* __restrict__ W_e2,
            const float* __restrict__ W_rad,
            float* __restrict__ rad0, float* __restrict__ rad1){
  __shared__ float feat[8][EFD];
  __shared__ float efl[8][CC];
  __shared__ float dist[8];
  int t = threadIdx.x;
  int e0 = blockIdx.x*8;
  if (t < 8){
    int e = e0+t;
    int s = ei[e], d = ei[EE+e];
    float dx = pos[s*3]-pos[d*3], dy = pos[s*3+1]-pos[d*3+1], dz = pos[s*3+2]-pos[d*3+2];
    dist[t] = sqrtf(dx*dx+dy*dy+dz*dz);
  }
  __syncthreads();
  const float step = 12.0f/599.0f;
  const float coeff = -0.5f/((2.0f*step)*(2.0f*step));
  for (int eidx=0; eidx<8; ++eidx){
    int e = e0+eidx;
    int zs = zn[ei[e]], zd = zn[ei[EE+e]];
    float de = dist[eidx];
    for (int k=t;k<EFD;k+=256){
      float v;
      if (k < NBASIS){ float u = de - k*step; v = expf(coeff*u*u); }
      else if (k < NBASIS+CC) v = src_emb[zs*CC + (k-NBASIS)];
      else v = dst_emb[zd*CC + (k-NBASIS-CC)];
      feat[eidx][k] = v;
    }
  }
  __syncthreads();
  int eidx = t>>5;
  int c0 = (t&31)*4;
  float a0=0,a1=0,a2=0,a3=0;
  for (int k=0;k<EFD;k++){
    float f = feat[eidx][k];
    const float4 w = *(const float4*)&W_e1[k*CC + c0];
    a0 += f*w.x; a1 += f*w.y; a2 += f*w.z; a3 += f*w.w;
  }
  efl[eidx][c0]=silu_f(a0); efl[eidx][c0+1]=silu_f(a1); efl[eidx][c0+2]=silu_f(a2); efl[eidx][c0+3]=silu_f(a3);
  __syncthreads();
  a0=a1=a2=a3=0;
  for (int k=0;k<CC;k++){
    float f = efl[eidx][k];
    const float4 w = *(const float4*)&W_e2[k*CC+c0];
    a0 += f*w.x; a1 += f*w.y; a2 += f*w.z; a3 += f*w.w;
  }
  __syncthreads();
  efl[eidx][c0]=silu_f(a0); efl[eidx][c0+1]=silu_f(a1); efl[eidx][c0+2]=silu_f(a2); efl[eidx][c0+3]=silu_f(a3);
  __syncthreads();
  #pragma unroll
  for (int l=0;l<2;l++){
    const float* Wr = W_rad + l*CC*CC;
    float r0=0,r1=0,r2=0,r3=0;
    for (int k=0;k<CC;k++){
      float f = efl[eidx][k];
      const float4 w = *(const float4*)&Wr[k*CC+c0];
      r0+=f*w.x; r1+=f*w.y; r2+=f*w.z; r3+=f*w.w;
    }
    float* out = l ? rad1 : rad0;
    *(float4*)&out[(e0+eidx)*CC + c0] = make_float4(r0,r1,r2,r3);
  }
}

// ---------------- equivariant RMS norm -> h ----------------
__global__ __launch_bounds__(256)
void k_rms(const float* __restrict__ x, const float* __restrict__ gamma, float* __restrict__ h){
  __shared__ float xs[LL][CC];
  __shared__ float ps[2][CC];
  int t = threadIdx.x, n = blockIdx.x;
  const float* xr = x + n*LL*CC;
  {
    float4* xs4 = (float4*)&xs[0][0];
    const float4* x4 = (const float4*)xr;
    for (int i=t;i<LL*CC/4;i+=256) xs4[i]=x4[i];
  }
  __syncthreads();
  int c = t&127, hf = t>>7;
  int r0 = hf?13:0, r1 = hf?LL:13;
  float s=0;
  for (int r=r0;r<r1;r++){ float v = xs[r][c]; s += v*v; }
  ps[hf][c]=s;
  __syncthreads();
  float rn = 1.0f/sqrtf((ps[0][c]+ps[1][c])*(1.0f/(float)LL) + 1e-6f);
  float g = gamma[c]*rn;
  float* hr = h + n*LL*CC;
  for (int r=r0;r<r1;r++) hr[r*CC+c] = xs[r][c]*g;
}

// ---------------- attention logits ----------------
__global__ __launch_bounds__(256)
void k_logits(const int* __restrict__ ei, const float* __restrict__ h,
              const float* __restrict__ rad, const float* __restrict__ wig,
              const float* __restrict__ Wa1, const float* __restrict__ wa2,
              float* __restrict__ logits){
  __shared__ float w0[8][LL];
  __shared__ float m0[8][CC];
  __shared__ float aS[8][HH*AA];
  int t = threadIdx.x;
  int e0 = blockIdx.x*8;
  for (int i=t;i<8*LL;i+=256){
    int eidx = i/LL, j = i - eidx*LL;
    w0[eidx][j] = wig[(e0+eidx)*625 + j];
  }
  __syncthreads();
  {
    int c = t&127, eg = t>>7;
    for (int j=0;j<4;j++){
      int e = e0 + eg*4 + j;
      int s = ei[e], d = ei[EE+e];
      const float* hs = h + s*LL*CC + c;
      const float* hd = h + d*LL*CC + c;
      float acc = 0;
      #pragma unroll
      for (int r=0;r<LL;r++) acc += w0[eg*4+j][r]*(hs[r*CC]+hd[r*CC]);
      m0[eg*4+j][c] = acc*rad[e*CC+c];
    }
  }
  __syncthreads();
  float accA[16];
  #pragma unroll
  for (int i=0;i<16;i++) accA[i]=0;
  for (int k=0;k<CC;k++){
    float wv0 = Wa1[k*512 + t];
    float wv1 = Wa1[k*512 + 256 + t];
    #pragma unroll
    for (int e=0;e<8;e++){
      float mv = m0[e][k];
      accA[e*2]   += mv*wv0;
      accA[e*2+1] += mv*wv1;
    }
  }
  #pragma unroll
  for (int e=0;e<8;e++){ aS[e][t]=silu_f(accA[e*2]); aS[e][256+t]=silu_f(accA[e*2+1]); }
  __syncthreads();
  if (t < 64){
    int eidx = t>>3, hh2 = t&7;
    float lg = 0;
    #pragma unroll
    for (int a=0;a<AA;a++) lg += aS[eidx][hh2*AA+a]*wa2[hh2*AA+a];
    logits[(e0+eidx)*HH + hh2] = lg;
  }
}

// ---------------- per-dst softmax ----------------
__global__ void k_softmax(const float* __restrict__ logits, const int* __restrict__ order,
                          const int* __restrict__ offsets, float* __restrict__ alpha){
  int n = blockIdx.x, t = threadIdx.x;
  if (t >= HH) return;
  int b = offsets[n], cnt = offsets[n+1]-b;
  float m = -1e30f;
  for (int i=0;i<cnt;i++) m = fmaxf(m, logits[order[b+i]*HH + t]);
  float z = 0;
  for (int i=0;i<cnt;i++) z += expf(logits[order[b+i]*HH + t] - m);
  float inv = 1.0f/(z + 1e-9f);
  for (int i=0;i<cnt;i++){
    int e = order[b+i];
    alpha[e*HH+t] = expf(logits[e*HH+t]-m)*inv;
  }
}

// ---------------- heavy attention: one block per destination node ----------------
// acc(dst) = sum_e WigT_e @ ((Wig_e @ (h[src]+h[dst]) * rad_e) @ Wv * alpha)
// x[dst]  += acc @ Wo   (W_out hoisted out of the edge sum)
__global__ __launch_bounds__(256)
void k_attn(const int* __restrict__ ei, const float* __restrict__ h,
            const float* __restrict__ wig_g, const float* __restrict__ rad,
            const float* __restrict__ alpha,
            const float* __restrict__ Wv, const float* __restrict__ Wo,
            const int* __restrict__ order, const int* __restrict__ offsets,
            float* __restrict__ x){
  __shared__ float wg [LL][LP];
  __shared__ float wgT[LL][LP];
  __shared__ float hsum[LL][CC];
  __shared__ float msgT[CC][LP];   // reused as accT after edge loop
  __shared__ float vrow[LL][CC];
  int n = blockIdx.x;
  int b = offsets[n];
  int cnt = offsets[n+1]-b;
  if (cnt == 0) return;
  int t = threadIdx.x;
  int dt = t & 31, rt = t >> 5;
  int d0 = dt*4;
  int i0 = rt*4;
  float acc[4][4];
  #pragma unroll
  for (int m=0;m<4;m++){ acc[m][0]=0; acc[m][1]=0; acc[m][2]=0; acc[m][3]=0; }

  for (int idx=0; idx<cnt; ++idx){
    int e = order[b+idx];
    const float* we = wig_g + e*625;
    for (int i=t;i<625;i+=256){
      int r = i/25, c = i-r*25;
      float v = we[i];
      wg[r][c] = v;     // wg[j][i]  = wigner[e][j][i]
      wgT[c][r] = v;    // wgT[j][i] = wigner[e][i][j]
    }
    {
      int s = ei[e], d = ei[EE+e];
      const float4* hs4 = (const float4*)(h + s*LL*CC);
      const float4* hd4 = (const float4*)(h + d*LL*CC);
      float4* hm4 = (float4*)&hsum[0][0];
      for (int i2=t;i2<LL*CC/4;i2+=256){
        float4 a4 = hs4[i2], b4 = hd4[i2];
        hm4[i2] = make_float4(a4.x+b4.x, a4.y+b4.y, a4.z+b4.z, a4.w+b4.w);
      }
    }
    float4 rad4 = *(const float4*)&rad[e*CC + d0];
    float al = alpha[e*HH + (d0>>4)];
    __syncthreads();

    // GEMM1: msg[i][c] = sum_j wig[i][j]*hsum[j][c]   (then *rad)
    float cm[4][4];
    #pragma unroll
    for (int m=0;m<4;m++){ cm[m][0]=0; cm[m][1]=0; cm[m][2]=0; cm[m][3]=0; }
    #pragma unroll 5
    for (int k=0;k<LL;k++){
      float4 av = *(const float4*)&wgT[k][i0];
      float4 bv = *(const float4*)&hsum[k][d0];
      fma16(cm, av, bv);
    }
    #pragma unroll
    for (int j=0;j<4;j++){
      float rj = (j==0)?rad4.x:((j==1)?rad4.y:((j==2)?rad4.z:rad4.w));
      *(float4*)&msgT[d0+j][i0] = make_float4(cm[0][j]*rj, cm[1][j]*rj, cm[2][j]*rj, cm[3][j]*rj);
    }
    __syncthreads();

    // GEMM2: v[i][d] = sum_c msg[i][c]*Wv[c][d]; scale alpha; store vrow
    #pragma unroll
    for (int m=0;m<4;m++){ cm[m][0]=0; cm[m][1]=0; cm[m][2]=0; cm[m][3]=0; }
    #pragma unroll 4
    for (int k=0;k<CC;k++){
      float4 av = *(const float4*)&msgT[k][i0];
      float4 bv = *(const float4*)&Wv[k*CC + d0];
      fma16(cm, av, bv);
    }
    #pragma unroll
    for (int m=0;m<4;m++){
      int i = i0+m;
      if (i < LL)
        *(float4*)&vrow[i][d0] = make_float4(cm[m][0]*al, cm[m][1]*al, cm[m][2]*al, cm[m][3]*al);
    }
    __syncthreads();

    // GEMM3: acc[i][c] += sum_j wig[j][i]*vrow[j][c]
    #pragma unroll 5
    for (int k=0;k<LL;k++){
      float4 av = *(const float4*)&wg[k][i0];
      float4 bv = *(const float4*)&vrow[k][d0];
      fma16(acc, av, bv);
    }
    __syncthreads();
  }

  // dump accT into msgT region
  #pragma unroll
  for (int j=0;j<4;j++)
    *(float4*)&msgT[d0+j][i0] = make_float4(acc[0][j], acc[1][j], acc[2][j], acc[3][j]);
  __syncthreads();

  // GEMM4: out[i][c'] = sum_d acc[i][d]*Wo[d][c']; residual into x
  float co[4][4];
  #pragma unroll
  for (int m=0;m<4;m++){ co[m][0]=0; co[m][1]=0; co[m][2]=0; co[m][3]=0; }
  #pragma unroll 4
  for (int k=0;k<CC;k++){
    float4 av = *(const float4*)&msgT[k][i0];
    float4 bv = *(const float4*)&Wo[k*CC + d0];
    fma16(co, av, bv);
  }
  #pragma unroll
  for (int m=0;m<4;m++){
    int i = i0+m;
    if (i < LL){
      float4 xv = *(float4*)&x[n*LL*CC + i*CC + d0];
      xv.x += co[m][0]; xv.y += co[m][1]; xv.z += co[m][2]; xv.w += co[m][3];
      *(float4*)&x[n*LL*CC + i*CC + d0] = xv;
    }
  }
}

// ---------------- gated FFN (rmsnorm fused) ----------------
__global__ __launch_bounds__(256)
void k_ffn(float* __restrict__ x, const float* __restrict__ gamma,
           const float* __restrict__ Wf1, const float* __restrict__ Wg,
           const float* __restrict__ Wf2){
  __shared__ float xs[LL][CC];
  __shared__ float tT[CC][LP];   // hT then hidT
  __shared__ float gs[FF];
  __shared__ float ps[2][CC];
  int t = threadIdx.x, n = blockIdx.x;
  float* xr = x + n*LL*CC;
  {
    float4* xs4 = (float4*)&xs[0][0];
    const float4* x4 = (const float4*)xr;
    for (int i=t;i<LL*CC/4;i+=256) xs4[i]=x4[i];
  }
  __syncthreads();
  int c = t&127, hf = t>>7;
  int r0 = hf?13:0, r1 = hf?LL:13;
  {
    float s=0;
    for (int r=r0;r<r1;r++){ float v=xs[r][c]; s += v*v; }
    ps[hf][c]=s;
  }
  __syncthreads();
  float rn = 1.0f/sqrtf((ps[0][c]+ps[1][c])*(1.0f/(float)LL) + 1e-6f);
  float gm = gamma[c]*rn;
  for (int r=r0;r<r1;r++) tT[c][r] = xs[r][c]*gm;
  __syncthreads();
  // gate from h[0,:]
  if (t < FF){
    float gv=0;
    for (int k=0;k<CC;k++) gv += tT[k][0]*Wg[k*FF+t];
    gs[t] = silu_f(gv);
  }
  int dt=t&31, rt=t>>5, d0=dt*4, i0=rt*4;
  float cm[4][4];
  #pragma unroll
  for (int m=0;m<4;m++){ cm[m][0]=0; cm[m][1]=0; cm[m][2]=0; cm[m][3]=0; }
  #pragma unroll 4
  for (int k=0;k<CC;k++){
    float4 av = *(const float4*)&tT[k][i0];
    float4 bv = *(const float4*)&Wf1[k*FF+d0];
    fma16(cm, av, bv);
  }
  __syncthreads();   // all GEMM1 reads of tT done; gs visible
  #pragma unroll
  for (int j=0;j<4;j++){
    float gj = gs[d0+j];
    *(float4*)&tT[d0+j][i0] = make_float4(cm[0][j]*gj, cm[1][j]*gj, cm[2][j]*gj, cm[3][j]*gj);
  }
  __syncthreads();
  float co[4][4];
  #pragma unroll
  for (int m=0;m<4;m++){ co[m][0]=0; co[m][1]=0; co[m][2]=0; co[m][3]=0; }
  #pragma unroll 4
  for (int k=0;k<FF;k++){
    float4 av = *(const float4*)&tT[k][i0];
    float4 bv = *(const float4*)&Wf2[k*CC+d0];
    fma16(co, av, bv);
  }
  #pragma unroll
  for (int m=0;m<4;m++){
    int i=i0+m;
    if (i<LL){
      float4 xv = *(float4*)&xs[i][d0];
      xv.x+=co[m][0]; xv.y+=co[m][1]; xv.z+=co[m][2]; xv.w+=co[m][3];
      *(float4*)&xr[i*CC+d0] = xv;
    }
  }
}

extern "C" void kernel_launch(void* const* d_in, const int* in_sizes, int n_in,
                              void* d_out, int out_size, void* d_ws, size_t ws_size,
                              hipStream_t stream){
  const int*   zn       = (const int*)  d_in[0];
  const float* pos      = (const float*)d_in[1];
  const int*   ei       = (const int*)  d_in[2];
  const float* wig      = (const float*)d_in[3];
  const float* atom_emb = (const float*)d_in[4];
  const float* src_emb  = (const float*)d_in[5];
  const float* dst_emb  = (const float*)d_in[6];
  const float* W_e1     = (const float*)d_in[7];
  const float* W_e2     = (const float*)d_in[8];
  const float* g_attn   = (const float*)d_in[9];
  const float* g_ffn    = (const float*)d_in[10];
  const float* W_rad    = (const float*)d_in[11];
  const float* W_a1     = (const float*)d_in[12];
  const float* w_a2     = (const float*)d_in[13];
  const float* W_val    = (const float*)d_in[14];
  const float* W_out    = (const float*)d_in[15];
  const float* W_f1     = (const float*)d_in[16];
  const float* W_g      = (const float*)d_in[17];
  const float* W_f2     = (const float*)d_in[18];
  float* x = (float*)d_out;

  char* w = (char*)d_ws;
  float* h      = (float*)w;  w += (size_t)NN*LL*CC*4;
  float* rad0   = (float*)w;  w += (size_t)EE*CC*4;
  float* rad1   = (float*)w;  w += (size_t)EE*CC*4;
  float* logits = (float*)w;  w += (size_t)EE*HH*4;
  float* alpha  = (float*)w;  w += (size_t)EE*HH*4;
  int* order    = (int*)w;    w += (size_t)EE*4;
  int* counts   = (int*)w;    w += (size_t)NN*4;
  int* offsets  = (int*)w;    w += (size_t)(NN+4)*4;
  int* cursor   = (int*)w;    w += (size_t)NN*4;

  hipMemsetAsync(counts, 0, NN*4, stream);
  hipMemsetAsync(cursor, 0, NN*4, stream);
  k_hist   <<<(EE+255)/256,256,0,stream>>>(ei, counts);
  k_scan   <<<1,256,0,stream>>>(counts, offsets);
  k_scatter<<<(EE+255)/256,256,0,stream>>>(ei, offsets, cursor, order);
  k_edge   <<<EE/8,256,0,stream>>>(ei, zn, pos, src_emb, dst_emb, W_e1, W_e2, W_rad, rad0, rad1);
  k_init_x <<<(NN*LL*CC)/256,256,0,stream>>>(zn, atom_emb, x);

  for (int l=0;l<2;l++){
    const float* radl = l? rad1:rad0;
    k_rms    <<<NN,256,0,stream>>>(x, g_attn + l*CC, h);
    k_logits <<<EE/8,256,0,stream>>>(ei, h, radl, wig, W_a1 + l*CC*HH*AA, w_a2 + l*HH*AA, logits);
    k_softmax<<<NN,64,0,stream>>>(logits, order, offsets, alpha);
    k_attn   <<<NN,256,0,stream>>>(ei, h, wig, radl, alpha, W_val + l*CC*HH*VV,
                                   W_out + l*HH*VV*CC, order, offsets, x);
    k_ffn    <<<NN,256,0,stream>>>(x, g_ffn + l*CC, W_f1 + l*CC*FF, W_g + l*CC*FF, W_f2 + l*FF*CC);
  }
}